// Round 17
// baseline (362.336 us; speedup 1.0000x reference)
//
#include <hip/hip_runtime.h>
#include <hip/hip_bf16.h>

#define B_    4
#define KL_   128
#define XL_   4096
#define DIM_  256
#define H_    8
#define HD_   32
#define PB_   8
#define NDIS_ 66
#define TDIM_ 768
#define SCALE_ 0.17677669529663687f
#define NS_   4
#define XCH_  (XL_ / NS_)
#define NCH_  64
#define KC2_  16

typedef float v4f __attribute__((ext_vector_type(4)));
typedef short v8s __attribute__((ext_vector_type(8)));

__device__ __forceinline__ unsigned short f2bf(float f) {
    __hip_bfloat16 h = __float2bfloat16(f);
    return __builtin_bit_cast(unsigned short, h);
}
__device__ __forceinline__ float bf2f(unsigned short u) {
    return __bfloat162float(__builtin_bit_cast(__hip_bfloat16, u));
}
__device__ __forceinline__ void cvt_hilo(float v, unsigned short& hi, unsigned short& lo) {
    hi = f2bf(v);
    lo = f2bf(v - bf2f(hi));
}

// ---------------------------------------------------------------------------
// cvt: f32 row-major -> hi/lo bf16 row-major
// ---------------------------------------------------------------------------
__global__ __launch_bounds__(256) void cvt_mat(const float* __restrict__ A,
                                               unsigned short* __restrict__ Ah,
                                               unsigned short* __restrict__ Al,
                                               size_t n4) {
    size_t i = ((size_t)blockIdx.x * 256 + threadIdx.x);
    if (i >= n4) return;
    float4 v = *(const float4*)&A[i * 4];
    ushort4 h, l;
    cvt_hilo(v.x, h.x, l.x);
    cvt_hilo(v.y, h.y, l.y);
    cvt_hilo(v.z, h.z, l.z);
    cvt_hilo(v.w, h.w, l.w);
    *(ushort4*)&Ah[i * 4] = h;
    *(ushort4*)&Al[i * 4] = l;
}

// cvt + transpose: W f32 [K][N] -> Wh/Wl bf16 [N][K]
__global__ __launch_bounds__(256) void cvt_wT(const float* __restrict__ W,
                                              unsigned short* __restrict__ Wh,
                                              unsigned short* __restrict__ Wl,
                                              int K, int N) {
    int n = blockIdx.x, k = threadIdx.x;
    float v = W[(size_t)k * N + n];
    unsigned short h, l;
    cvt_hilo(v, h, l);
    Wh[(size_t)n * K + k] = h;
    Wl[(size_t)n * K + k] = l;
}

// cvt k_q slice: qkv_k q-part -> Kqg hi/lo [bh][k][32]
__global__ __launch_bounds__(256) void cvt_kq(const float* __restrict__ qkv_k,
                                              unsigned short* __restrict__ Kqh_g,
                                              unsigned short* __restrict__ Kql_g) {
    const int bh = blockIdx.x;
    const int b = bh >> 3, h = bh & 7;
    const int tid = threadIdx.x;
    const int k = tid >> 1, dg = (tid & 1) * 16;
    const float* src = &qkv_k[((size_t)(b * KL_ + k)) * TDIM_ + h * HD_ + dg];
    unsigned short hi[16], lo[16];
#pragma unroll
    for (int j4 = 0; j4 < 4; ++j4) {
        float4 v = *(const float4*)&src[j4 * 4];
        cvt_hilo(v.x, hi[j4 * 4 + 0], lo[j4 * 4 + 0]);
        cvt_hilo(v.y, hi[j4 * 4 + 1], lo[j4 * 4 + 1]);
        cvt_hilo(v.z, hi[j4 * 4 + 2], lo[j4 * 4 + 2]);
        cvt_hilo(v.w, hi[j4 * 4 + 3], lo[j4 * 4 + 3]);
    }
    unsigned short* dh = &Kqh_g[((size_t)bh * KL_ + k) * HD_ + dg];
    unsigned short* dl = &Kql_g[((size_t)bh * KL_ + k) * HD_ + dg];
    *(uint4*)&dh[0] = *(uint4*)&hi[0];
    *(uint4*)&dh[8] = *(uint4*)&hi[8];
    *(uint4*)&dl[0] = *(uint4*)&lo[0];
    *(uint4*)&dl[8] = *(uint4*)&lo[8];
}

// ---------------------------------------------------------------------------
// Split-bf16 MFMA GEMM (unchanged)
// ---------------------------------------------------------------------------
__global__ __launch_bounds__(256) void gemm_mfma(const unsigned short* __restrict__ Ah,
                                                 const unsigned short* __restrict__ Al,
                                                 const unsigned short* __restrict__ Bh,
                                                 const unsigned short* __restrict__ Bl,
                                                 float* __restrict__ C,
                                                 const float* __restrict__ bias,
                                                 int M, int N, int K) {
    __shared__ __align__(16) unsigned short Ah_s[128][40];
    __shared__ __align__(16) unsigned short Al_s[128][40];
    __shared__ __align__(16) unsigned short Bh_s[128][40];
    __shared__ __align__(16) unsigned short Bl_s[128][40];
    const int tid = threadIdx.x;
    const int w = tid >> 6, lane = tid & 63;
    const int c = lane & 15, q = lane >> 4;
    const int bm = blockIdx.y * 128, bn = blockIdx.x * 128;
    const int srow = tid >> 1, shf = (tid & 1) * 16;

    v4f acc[2][8] = {};
    for (int k0 = 0; k0 < K; k0 += 32) {
        __syncthreads();
        {
            const size_t ab = (size_t)(bm + srow) * K + k0 + shf;
            *(uint4*)&Ah_s[srow][shf] = *(const uint4*)&Ah[ab];
            *(uint4*)&Ah_s[srow][shf + 8] = *(const uint4*)&Ah[ab + 8];
            *(uint4*)&Al_s[srow][shf] = *(const uint4*)&Al[ab];
            *(uint4*)&Al_s[srow][shf + 8] = *(const uint4*)&Al[ab + 8];
            const size_t bb = (size_t)(bn + srow) * K + k0 + shf;
            *(uint4*)&Bh_s[srow][shf] = *(const uint4*)&Bh[bb];
            *(uint4*)&Bh_s[srow][shf + 8] = *(const uint4*)&Bh[bb + 8];
            *(uint4*)&Bl_s[srow][shf] = *(const uint4*)&Bl[bb];
            *(uint4*)&Bl_s[srow][shf + 8] = *(const uint4*)&Bl[bb + 8];
        }
        __syncthreads();
        v8s afh[2], afl[2];
#pragma unroll
        for (int mt = 0; mt < 2; ++mt) {
            afh[mt] = *(v8s*)&Ah_s[w * 32 + mt * 16 + c][q * 8];
            afl[mt] = *(v8s*)&Al_s[w * 32 + mt * 16 + c][q * 8];
        }
#pragma unroll
        for (int nt = 0; nt < 8; ++nt) {
            v8s bfh = *(v8s*)&Bh_s[nt * 16 + c][q * 8];
            v8s bfl = *(v8s*)&Bl_s[nt * 16 + c][q * 8];
#pragma unroll
            for (int mt = 0; mt < 2; ++mt) {
                acc[mt][nt] = __builtin_amdgcn_mfma_f32_16x16x32_bf16(afl[mt], bfh, acc[mt][nt], 0, 0, 0);
                acc[mt][nt] = __builtin_amdgcn_mfma_f32_16x16x32_bf16(afh[mt], bfl, acc[mt][nt], 0, 0, 0);
                acc[mt][nt] = __builtin_amdgcn_mfma_f32_16x16x32_bf16(afh[mt], bfh, acc[mt][nt], 0, 0, 0);
            }
        }
    }
#pragma unroll
    for (int mt = 0; mt < 2; ++mt) {
#pragma unroll
        for (int nt = 0; nt < 8; ++nt) {
            int col = bn + nt * 16 + c;
            float bv = bias ? bias[col] : 0.0f;
#pragma unroll
            for (int r = 0; r < 4; ++r) {
                int row = bm + w * 32 + mt * 16 + q * 4 + r;
                C[(size_t)row * N + col] = acc[mt][nt][r] + bv;
            }
        }
    }
}

// ---------------------------------------------------------------------------
// 64x64 f32 GEMM (small-M)
// ---------------------------------------------------------------------------
__global__ __launch_bounds__(256) void gemm64(const float* __restrict__ A,
                                              const float* __restrict__ Bw,
                                              float* __restrict__ C,
                                              const float* __restrict__ bias,
                                              int M, int N, int K) {
    __shared__ __align__(16) float As[16][68];
    __shared__ __align__(16) float Bs[16][64];
    const int tid = threadIdx.x;
    const int tx = tid & 15, ty = tid >> 4;
    const int bn = blockIdx.x * 64, bm = blockIdx.y * 64;
    const int am = tid >> 2, ac = tid & 3;
    float acc[4][4] = {};
    for (int k0 = 0; k0 < K; k0 += 16) {
        float4 a4 = *(const float4*)&A[(size_t)(bm + am) * K + k0 + ac * 4];
        As[ac * 4 + 0][am] = a4.x;
        As[ac * 4 + 1][am] = a4.y;
        As[ac * 4 + 2][am] = a4.z;
        As[ac * 4 + 3][am] = a4.w;
        *(float4*)&Bs[ty][tx * 4] = *(const float4*)&Bw[(size_t)(k0 + ty) * N + bn + tx * 4];
        __syncthreads();
#pragma unroll
        for (int kk = 0; kk < 16; ++kk) {
            float4 av = *(const float4*)&As[kk][ty * 4];
            float4 bv = *(const float4*)&Bs[kk][tx * 4];
            float a[4] = {av.x, av.y, av.z, av.w};
            float b[4] = {bv.x, bv.y, bv.z, bv.w};
#pragma unroll
            for (int i = 0; i < 4; ++i)
#pragma unroll
                for (int j = 0; j < 4; ++j) acc[i][j] += a[i] * b[j];
        }
        __syncthreads();
    }
#pragma unroll
    for (int i = 0; i < 4; ++i) {
        int m = bm + ty * 4 + i;
#pragma unroll
        for (int j = 0; j < 4; ++j) {
            int n = bn + tx * 4 + j;
            float v = acc[i][j];
            if (bias) v += bias[n];
            C[(size_t)m * N + n] = v;
        }
    }
}

// ===========================================================================
// K1 v5: 64-x blocks (high occupancy) + 2-deep register prefetch (ILP).
// ===========================================================================
__global__ __launch_bounds__(256) void score_bins_mfma5(const float* __restrict__ qkv_x,
                                                        const unsigned short* __restrict__ Kqh_g,
                                                        const unsigned short* __restrict__ Kql_g,
                                                        const int* __restrict__ rd,
                                                        const int* __restrict__ polar_pos,
                                                        const int* __restrict__ att_mask,
                                                        const float* __restrict__ dis_embed,
                                                        __hip_bfloat16* __restrict__ Sg,
                                                        float* __restrict__ binspart) {
    const int b = blockIdx.z, h = blockIdx.y, xc = blockIdx.x;
    const int x0 = xc * 64;
    const int tid = threadIdx.x;
    const int w = tid >> 6, lane = tid & 63;
    const int c15 = lane & 15, q = lane >> 4;
    const size_t bh = (size_t)(b * H_ + h);

    __shared__ unsigned int mskb[64][5];
    __shared__ float de_h[NDIS_];
    __shared__ float binsL[8][4][16][PB_];

    // mask -> bit tile
    {
        int xr = tid >> 2, kg = tid & 3;
        size_t gb = (bh * XL_ + x0 + xr) * KL_ + kg * 32;
        unsigned bits = 0;
#pragma unroll
        for (int i = 0; i < 8; ++i) {
            int4 m4 = *(const int4*)&att_mask[gb + i * 4];
            bits |= (m4.x ? 1u : 0u) << (i * 4 + 0);
            bits |= (m4.y ? 1u : 0u) << (i * 4 + 1);
            bits |= (m4.z ? 1u : 0u) << (i * 4 + 2);
            bits |= (m4.w ? 1u : 0u) << (i * 4 + 3);
        }
        mskb[xr][kg] = bits;
    }
    if (tid < NDIS_) de_h[tid] = dis_embed[tid * H_ + h];
    __syncthreads();

    // A-fragment in registers (own x row, hi/lo)
    v8s axh, axl;
    {
        const float* src = &qkv_x[((size_t)b * XL_ + x0 + w * 16 + c15) * TDIM_ + DIM_ + h * HD_ + q * 8];
        float4 v0 = *(const float4*)&src[0];
        float4 v1 = *(const float4*)&src[4];
        float vv[8] = {v0.x, v0.y, v0.z, v0.w, v1.x, v1.y, v1.z, v1.w};
#pragma unroll
        for (int j = 0; j < 8; ++j) {
            unsigned short hi, lo;
            cvt_hilo(vv[j], hi, lo);
            ((short*)&axh)[j] = (short)hi;
            ((short*)&axl)[j] = (short)lo;
        }
    }

    const int xw = x0 + w * 16;

    // 2-deep register prefetch pipeline over nt
    v8s bqh[2], bql[2];
    int4 r4[2], p4[2];
    auto load_nt = [&](int nt, int s) {
        const int k = nt * 16 + c15;
        const size_t kqoff = (bh * KL_ + k) * HD_ + q * 8;
        bqh[s] = *(const v8s*)&Kqh_g[kqoff];
        bql[s] = *(const v8s*)&Kql_g[kqoff];
        const size_t rowoff = ((size_t)(b * KL_ + k)) * XL_ + xw + q * 4;
        r4[s] = *(const int4*)&rd[rowoff];
        p4[s] = *(const int4*)&polar_pos[rowoff];
    };
    load_nt(0, 0);

#pragma unroll
    for (int nt = 0; nt < 8; ++nt) {
        const int s = nt & 1;
        if (nt < 7) load_nt(nt + 1, s ^ 1);

        const int k = nt * 16 + c15;
        v4f D = {0.f, 0.f, 0.f, 0.f};
        D = __builtin_amdgcn_mfma_f32_16x16x32_bf16(axl, bqh[s], D, 0, 0, 0);
        D = __builtin_amdgcn_mfma_f32_16x16x32_bf16(axh, bql[s], D, 0, 0, 0);
        D = __builtin_amdgcn_mfma_f32_16x16x32_bf16(axh, bqh[s], D, 0, 0, 0);

        int rv[4] = {r4[s].x, r4[s].y, r4[s].z, r4[s].w};
        int pv[4] = {p4[s].x, p4[s].y, p4[s].z, p4[s].w};

        float bins[PB_] = {};
        ushort4 pack;
#pragma unroll
        for (int r = 0; r < 4; ++r) {
            float sc = D[r] * SCALE_;
            float a = fabsf(sc);
            int pp = pv[r];
#pragma unroll
            for (int pb = 0; pb < PB_; ++pb) bins[pb] += (pp == pb) ? a : 0.0f;
            int xloc = w * 16 + q * 4 + r;
            int mbit = (mskb[xloc][k >> 5] >> (k & 31)) & 1;
            float sp = (mbit ? -1e6f : sc) + de_h[rv[r]];
            ((unsigned short*)&pack)[r] = f2bf(sp);
        }
        *(ushort4*)((unsigned short*)Sg + (bh * KL_ + k) * XL_ + xw + q * 4) = pack;

#pragma unroll
        for (int pb = 0; pb < PB_; ++pb) {
            bins[pb] += __shfl_xor(bins[pb], 16);
            bins[pb] += __shfl_xor(bins[pb], 32);
        }
        if (q == 0) {
#pragma unroll
            for (int pb = 0; pb < PB_; ++pb) binsL[nt][w][c15][pb] = bins[pb];
        }
    }
    __syncthreads();
    {
        int k = tid >> 1, half = tid & 1;
        int nt = k >> 4, c = k & 15;
        float4 s = {0.f, 0.f, 0.f, 0.f};
#pragma unroll
        for (int w4 = 0; w4 < 4; ++w4) {
            float4 v = *(float4*)&binsL[nt][w4][c][half * 4];
            s.x += v.x; s.y += v.y; s.z += v.z; s.w += v.w;
        }
        *(float4*)&binspart[(bh * KL_ + k) * (NCH_ * PB_) + xc * PB_ + half * 4] = s;
    }
}

// K2: argmax over 64 chunks
__global__ __launch_bounds__(256) void bins_argmax(const float* __restrict__ binspart,
                                                   int* __restrict__ main_ori) {
    const int w = threadIdx.x >> 6, lane = threadIdx.x & 63;
    const int row = blockIdx.x * 4 + w;
    const float* bp = &binspart[(size_t)row * (NCH_ * PB_) + lane * PB_];
    float s[PB_];
#pragma unroll
    for (int pb = 0; pb < PB_; ++pb) s[pb] = bp[pb];
#pragma unroll
    for (int m = 1; m < 64; m <<= 1)
#pragma unroll
        for (int pb = 0; pb < PB_; ++pb) s[pb] += __shfl_xor(s[pb], m);
    if (lane == 0) {
        float best = s[0];
        int bi = 0;
#pragma unroll
        for (int pb = 1; pb < PB_; ++pb)
            if (s[pb] > best) { best = s[pb]; bi = pb; }
        main_ori[row] = bi;
    }
}

// ===========================================================================
// K3 v3: flash_cached3 — register-double-buffered V/pol staging.
// ===========================================================================
__global__ __launch_bounds__(256) void flash_cached3(const float* __restrict__ qkv_x,
                                                     const __hip_bfloat16* __restrict__ Sg,
                                                     const int* __restrict__ polar_pos,
                                                     const float* __restrict__ polar_emb,
                                                     const int* __restrict__ main_ori,
                                                     float* __restrict__ part) {
    const int b = blockIdx.z, h = blockIdx.y;
    const int kch = blockIdx.x / NS_, xc = blockIdx.x % NS_;
    const int k0 = kch * KC2_;
    const int tid = threadIdx.x;
    const int ki = tid >> 4, xt = tid & 15;

    __shared__ __align__(16) float4 vs[64][9];
    __shared__ int pol_s[KC2_][68];
    __shared__ float pe[PB_];

    if (tid < PB_) pe[tid] = polar_emb[tid];
    const size_t xbase = (size_t)b * XL_;
    const size_t bh = (size_t)(b * H_ + h);
    const size_t row_k = bh * KL_ + k0 + ki;
    const int mo = main_ori[row_k];
    const int xbeg = xc * XCH_;

    // staging assignments
    const int vrow0 = tid >> 3, vc0 = tid & 7;          // vs[vrow0][vc0]
    const int vrow1 = 32 + (tid >> 3), vc1 = tid & 7;   // vs[vrow1][vc1]
    const int pkk = tid >> 4, pcc = tid & 15;           // pol_s[pkk][pcc*4]

    float4 rv0, rv1;
    int4 rp;
    auto load_tile = [&](int t) {
        const int x0 = xbeg + t * 64;
        rv0 = *(const float4*)&qkv_x[(xbase + x0 + vrow0) * TDIM_ + 2 * DIM_ + h * HD_ + vc0 * 4];
        rv1 = *(const float4*)&qkv_x[(xbase + x0 + vrow1) * TDIM_ + 2 * DIM_ + h * HD_ + vc1 * 4];
        rp = *(const int4*)&polar_pos[(size_t)(b * KL_ + k0 + pkk) * XL_ + x0 + pcc * 4];
    };
    load_tile(0);

    float l = 0.f;
    float4 acc[8] = {};
    for (int t = 0; t < XCH_ / 64; ++t) {
        const int x0 = xbeg + t * 64;
        __syncthreads();                // previous tile's consumers done
        vs[vrow0][vc0] = rv0;
        vs[vrow1][vc1] = rv1;
        *(int4*)&pol_s[pkk][pcc * 4] = rp;
        if (t + 1 < XCH_ / 64) load_tile(t + 1);   // overlap with compute
        __syncthreads();                // LDS ready
#pragma unroll
        for (int j = 0; j < 4; ++j) {
            int xl = xt + 16 * j;
            int x = x0 + xl;
            float sp = __bfloat162float(Sg[row_k * XL_ + x]);
            int pp = pol_s[ki][xl];
            int np = pp - mo;
            np += (np >> 31) & PB_;
            float p = __expf(sp + pe[np]);
            l += p;
#pragma unroll
            for (int c = 0; c < 8; ++c) {
                float4 v = vs[xl][c];
                acc[c].x += p * v.x; acc[c].y += p * v.y;
                acc[c].z += p * v.z; acc[c].w += p * v.w;
            }
        }
    }
#pragma unroll
    for (int m = 1; m < 16; m <<= 1) {
        l += __shfl_xor(l, m, 16);
#pragma unroll
        for (int c = 0; c < 8; ++c) {
            acc[c].x += __shfl_xor(acc[c].x, m, 16);
            acc[c].y += __shfl_xor(acc[c].y, m, 16);
            acc[c].z += __shfl_xor(acc[c].z, m, 16);
            acc[c].w += __shfl_xor(acc[c].w, m, 16);
        }
    }
    if (xt == 0) {
        float* dst = &part[(size_t)(row_k * NS_ + xc) * 36];
#pragma unroll
        for (int c = 0; c < 8; ++c) *(float4*)&dst[c * 4] = acc[c];
        dst[32] = l;
    }
}

// K4: merge
__global__ __launch_bounds__(256) void merge_cached(const float* __restrict__ part,
                                                    float* __restrict__ kout_pre) {
    const int tid = threadIdx.x;
    const int ri = tid >> 5, d = tid & 31;
    const int row = blockIdx.x * 8 + ri;
    float l = 0.f, a = 0.f;
#pragma unroll
    for (int c = 0; c < NS_; ++c) {
        const float* p = &part[(size_t)(row * NS_ + c) * 36];
        l += p[32];
        a += p[d];
    }
    int k = row & (KL_ - 1);
    int bh = row >> 7;
    int h = bh & (H_ - 1), b = bh >> 3;
    kout_pre[(size_t)(b * KL_ + k) * DIM_ + h * HD_ + d] = a / l;
}

// ===========================================================================
// attn_x_mfma (unchanged; writes hi/lo proj operands directly)
// ===========================================================================
__global__ __launch_bounds__(256) void attn_x_mfma(const float* __restrict__ qkv_x,
                                                   const float* __restrict__ qkv_k,
                                                   const int* __restrict__ rd,
                                                   const int* __restrict__ polar_pos,
                                                   const int* __restrict__ att_mask,
                                                   const float* __restrict__ dis_embed,
                                                   const float* __restrict__ polar_emb,
                                                   const int* __restrict__ main_ori,
                                                   unsigned short* __restrict__ oh,
                                                   unsigned short* __restrict__ ol) {
    const int b = blockIdx.z, h = blockIdx.y;
    const int x0 = blockIdx.x * 64;
    const int tid = threadIdx.x;
    const int wave = tid >> 6, lane = tid & 63;
    const int c = lane & 15, q = lane >> 4;

    __shared__ __align__(16) unsigned short Kk_s[KL_][40];
    __shared__ __align__(16) unsigned short VT_s[HD_][136];
    __shared__ __align__(16) unsigned short P_s[4][16][136];
    __shared__ unsigned short rp_s[KL_][72];
    __shared__ float de_h[NDIS_];
    __shared__ float pe[PB_];
    __shared__ int mo_s[KL_];

    const size_t bh = (size_t)(b * H_ + h);
    if (tid < NDIS_) de_h[tid] = dis_embed[tid * H_ + h];
    if (tid < PB_) pe[tid] = polar_emb[tid];
    if (tid < KL_) mo_s[tid] = main_ori[bh * KL_ + tid];

    {
        int row = tid >> 1, half = tid & 1;
        const float* src = &qkv_k[(size_t)(b * KL_ + row) * TDIM_ + h * HD_ + half * 16];
#pragma unroll
        for (int j = 0; j < 16; ++j) Kk_s[row][half * 16 + j] = f2bf(src[DIM_ + j]);
#pragma unroll
        for (int j = 0; j < 16; ++j) VT_s[half * 16 + j][row] = f2bf(src[2 * DIM_ + j]);
    }
    __syncthreads();

#pragma unroll
    for (int i = 0; i < 8; ++i) {
        int id = tid + 256 * i;
        int k = id >> 4, cc = id & 15;
        size_t gb = (size_t)(b * KL_ + k) * XL_ + x0 + cc * 4;
        int4 r4 = *(const int4*)&rd[gb];
        int4 p4 = *(const int4*)&polar_pos[gb];
        int mo = mo_s[k];
        int n0 = p4.x - mo; n0 += (n0 >> 31) & PB_;
        int n1 = p4.y - mo; n1 += (n1 >> 31) & PB_;
        int n2 = p4.z - mo; n2 += (n2 >> 31) & PB_;
        int n3 = p4.w - mo; n3 += (n3 >> 31) & PB_;
        rp_s[k][cc * 4 + 0] = (unsigned short)(r4.x | (n0 << 8));
        rp_s[k][cc * 4 + 1] = (unsigned short)(r4.y | (n1 << 8));
        rp_s[k][cc * 4 + 2] = (unsigned short)(r4.z | (n2 << 8));
        rp_s[k][cc * 4 + 3] = (unsigned short)(r4.w | (n3 << 8));
    }
    __syncthreads();
#pragma unroll
    for (int i = 0; i < 8; ++i) {
        int id = tid + 256 * i;
        int xr = id >> 5, kc = id & 31;
        int4 m4 = *(const int4*)&att_mask[(bh * XL_ + x0 + xr) * KL_ + kc * 4];
        if (m4.x) rp_s[kc * 4 + 0][xr] |= 0x8000;
        if (m4.y) rp_s[kc * 4 + 1][xr] |= 0x8000;
        if (m4.z) rp_s[kc * 4 + 2][xr] |= 0x8000;
        if (m4.w) rp_s[kc * 4 + 3][xr] |= 0x8000;
    }
    __syncthreads();

    v8s aq;
    {
        const float* qp = &qkv_x[(size_t)(b * XL_ + x0 + wave * 16 + c) * TDIM_ + h * HD_ + q * 8];
        float4 q0 = *(const float4*)&qp[0];
        float4 q1 = *(const float4*)&qp[4];
        aq[0] = (short)f2bf(q0.x); aq[1] = (short)f2bf(q0.y);
        aq[2] = (short)f2bf(q0.z); aq[3] = (short)f2bf(q0.w);
        aq[4] = (short)f2bf(q1.x); aq[5] = (short)f2bf(q1.y);
        aq[6] = (short)f2bf(q1.z); aq[7] = (short)f2bf(q1.w);
    }

    v4f S[8];
#pragma unroll
    for (int t = 0; t < 8; ++t) {
        v8s bk = *(v8s*)&Kk_s[t * 16 + c][q * 8];
        S[t] = __builtin_amdgcn_mfma_f32_16x16x32_bf16(aq, bk, (v4f){0.f, 0.f, 0.f, 0.f}, 0, 0, 0);
    }

    const int xloc = wave * 16;
    float lr[4] = {0.f, 0.f, 0.f, 0.f};
#pragma unroll
    for (int t = 0; t < 8; ++t) {
#pragma unroll
        for (int r = 0; r < 4; ++r) {
            int krow = t * 16 + c;
            int xrow = q * 4 + r;
            unsigned short rp = rp_s[krow][xloc + xrow];
            float sval = S[t][r] * SCALE_;
            float tval = ((rp & 0x8000) ? -25.0f : sval) + de_h[rp & 0x7f] + pe[(rp >> 8) & 7];
            float p = __expf(tval);
            unsigned short pb = f2bf(p);
            P_s[wave][xrow][krow] = pb;
            lr[r] += bf2f(pb);
        }
    }
#pragma unroll
    for (int r = 0; r < 4; ++r) {
#pragma unroll
        for (int m = 1; m < 16; m <<= 1) lr[r] += __shfl_xor(lr[r], m);
    }
    __syncthreads();

    v4f O0 = {0.f, 0.f, 0.f, 0.f}, O1 = {0.f, 0.f, 0.f, 0.f};
#pragma unroll
    for (int kc = 0; kc < 4; ++kc) {
        v8s ap = *(v8s*)&P_s[wave][c][kc * 32 + q * 8];
        v8s bv0 = *(v8s*)&VT_s[c][kc * 32 + q * 8];
        v8s bv1 = *(v8s*)&VT_s[16 + c][kc * 32 + q * 8];
        O0 = __builtin_amdgcn_mfma_f32_16x16x32_bf16(ap, bv0, O0, 0, 0, 0);
        O1 = __builtin_amdgcn_mfma_f32_16x16x32_bf16(ap, bv1, O1, 0, 0, 0);
    }

#pragma unroll
    for (int r = 0; r < 4; ++r) {
        int xg = x0 + wave * 16 + q * 4 + r;
        float inv = 1.0f / lr[r];
        size_t obase = (size_t)(b * XL_ + xg) * DIM_ + h * HD_;
        float v0 = O0[r] * inv;
        float v1 = O1[r] * inv;
        unsigned short h0, l0, h1, l1;
        cvt_hilo(v0, h0, l0);
        cvt_hilo(v1, h1, l1);
        oh[obase + c] = h0;
        ol[obase + c] = l0;
        oh[obase + 16 + c] = h1;
        ol[obase + 16 + c] = l1;
    }
}

// ---------------------------------------------------------------------------
extern "C" void kernel_launch(void* const* d_in, const int* in_sizes, int n_in,
                              void* d_out, int out_size, void* d_ws, size_t ws_size,
                              hipStream_t stream) {
    const float* x         = (const float*)d_in[0];
    const float* kernal    = (const float*)d_in[1];
    const int* rd          = (const int*)d_in[2];
    const int* polar_pos   = (const int*)d_in[3];
    const int* att_mask    = (const int*)d_in[4];
    const float* W_qkv     = (const float*)d_in[5];
    const float* dis_embed = (const float*)d_in[6];
    const float* polar_emb = (const float*)d_in[7];
    const float* W_proj    = (const float*)d_in[8];
    const float* b_proj    = (const float*)d_in[9];
    float* out             = (float*)d_out;

    char* base = (char*)d_ws;
    size_t off = 0;
    auto alloc = [&](size_t bytes) { void* p = base + off; off = (off + bytes + 255) & ~255ULL; return p; };
    float* qkv_x    = (float*)alloc((size_t)B_ * XL_ * TDIM_ * 4);
    float* qkv_k    = (float*)alloc((size_t)B_ * KL_ * TDIM_ * 4);
    float* xout_pre = (float*)alloc((size_t)B_ * XL_ * DIM_ * 4);   // binspart alias
    float* kout_pre = (float*)alloc((size_t)B_ * KL_ * DIM_ * 4);
    int* main_ori   = (int*)alloc(B_ * H_ * KL_ * 4);
    float* part     = (float*)alloc((size_t)B_ * H_ * KL_ * NS_ * 36 * 4);
    __hip_bfloat16* Sg = (__hip_bfloat16*)alloc((size_t)B_ * H_ * KL_ * XL_ * 2);
    unsigned short* wph = (unsigned short*)alloc((size_t)DIM_ * DIM_ * 2);
    unsigned short* wpl = (unsigned short*)alloc((size_t)DIM_ * DIM_ * 2);

    float* binspart = xout_pre;
    const size_t MX = (size_t)B_ * XL_;
    unsigned short* xh = (unsigned short*)Sg;
    unsigned short* xl_ = xh + MX * DIM_;
    unsigned short* wqh = (unsigned short*)part;
    unsigned short* wql = wqh + (size_t)TDIM_ * DIM_;
    unsigned short* kqh_g = wqh + 2 * (size_t)TDIM_ * DIM_;
    unsigned short* kql_g = kqh_g + (size_t)B_ * H_ * KL_ * HD_;
    unsigned short* oh = (unsigned short*)Sg;
    unsigned short* ol = oh + MX * DIM_;

    // --- operand conversion ---
    cvt_mat<<<dim3((MX * DIM_ / 4 + 255) / 256), 256, 0, stream>>>(x, xh, xl_, MX * DIM_ / 4);
    cvt_wT<<<dim3(TDIM_), DIM_, 0, stream>>>(W_qkv, wqh, wql, DIM_, TDIM_);
    cvt_wT<<<dim3(DIM_), DIM_, 0, stream>>>(W_proj, wph, wpl, DIM_, DIM_);

    // --- qkv projections ---
    gemm_mfma<<<dim3(TDIM_ / 128, MX / 128), 256, 0, stream>>>(
        xh, xl_, wqh, wql, qkv_x, nullptr, MX, TDIM_, DIM_);
    gemm64<<<dim3(TDIM_ / 64, (B_ * KL_) / 64), 256, 0, stream>>>(
        kernal, W_qkv, qkv_k, nullptr, B_ * KL_, TDIM_, DIM_);
    cvt_kq<<<dim3(B_ * H_), 256, 0, stream>>>(qkv_k, kqh_g, kql_g);

    // --- k-direction ---
    score_bins_mfma5<<<dim3(NCH_, H_, B_), 256, 0, stream>>>(
        qkv_x, kqh_g, kql_g, rd, polar_pos, att_mask, dis_embed, Sg, binspart);
    bins_argmax<<<dim3(B_ * H_ * KL_ / 4), 256, 0, stream>>>(binspart, main_ori);
    flash_cached3<<<dim3((KL_ / KC2_) * NS_, H_, B_), 256, 0, stream>>>(
        qkv_x, Sg, polar_pos, polar_emb, main_ori, part);
    merge_cached<<<dim3(B_ * H_ * KL_ / 8), 256, 0, stream>>>(part, kout_pre);

    // --- x-direction ---
    attn_x_mfma<<<dim3(XL_ / 64, H_, B_), 256, 0, stream>>>(
        qkv_x, qkv_k, rd, polar_pos, att_mask, dis_embed, polar_emb, main_ori, oh, ol);

    // --- output projections ---
    gemm_mfma<<<dim3(DIM_ / 128, MX / 128), 256, 0, stream>>>(
        oh, ol, wph, wpl, out, b_proj, MX, DIM_, DIM_);
    gemm64<<<dim3(DIM_ / 64, (B_ * KL_) / 64), 256, 0, stream>>>(
        kout_pre, W_proj, out + (size_t)B_ * XL_ * DIM_, b_proj, B_ * KL_, DIM_, DIM_);
}